// Round 9
// baseline (668.266 us; speedup 1.0000x reference)
//
#include <hip/hip_runtime.h>
#include <math.h>

// ---------------- problem constants ----------------
constexpr int T_ = 2048;   // tokens (B*S)
constexpr int D_ = 1024;   // model dim
constexpr int E_ = 16;     // experts
constexpr int H_ = 1024;   // expert hidden
constexpr int K_ = 4;      // top-k
constexpr float EPS_ = 1e-6f;

// ---------------- tiling: BM=128, BN=64, BK=32, 4 waves (2x2), wave tile 64x32 ----
// 2-phase double-buffered LDS pipeline (T3 minimal): stage k+1 during MFMA of k.
constexpr int FMT = 16;      // worst-case M-tiles
constexpr int FNT = 16;      // N-tiles of 64 over 1024

// ---------------- workspace layout (bytes) ----------------
constexpr size_t FWS_CNT   = 0;                                   // E ints
constexpr size_t FWS_LISTP = 256;
constexpr size_t FWS_LISTW = FWS_LISTP + (size_t)E_ * T_ * 4;
constexpr size_t FWS_NSC   = FWS_LISTW + (size_t)E_ * T_ * 4;
constexpr size_t FWS_XHI   = FWS_NSC  + (size_t)T_ * E_ * 4;      // T*D shorts
constexpr size_t FWS_XLO   = FWS_XHI  + (size_t)T_ * D_ * 2;
constexpr size_t FWS_AHI   = FWS_XLO  + (size_t)T_ * D_ * 2;      // T*K*H shorts
constexpr size_t FWS_ALO   = FWS_AHI  + (size_t)T_ * K_ * H_ * 2;
constexpr size_t FWS_W1S   = FWS_ALO  + (size_t)T_ * K_ * H_ * 2; // swizzled hi/lo
constexpr size_t FWS_W3S   = FWS_W1S  + (size_t)E_ * D_ * H_ * 4;
constexpr size_t FWS_W2S   = FWS_W3S  + (size_t)E_ * D_ * H_ * 4;
constexpr size_t FWS_NEED  = FWS_W2S  + (size_t)E_ * H_ * D_ * 4; // ~232 MB (fits, r5/r7)

using short8  = __attribute__((ext_vector_type(8))) short;
using floatx4 = __attribute__((ext_vector_type(4))) float;

#define MFMA16(a, b, c) __builtin_amdgcn_mfma_f32_16x16x32_bf16((a), (b), (c), 0, 0, 0)

__device__ __forceinline__ float silu_f(float h) {
    return h / (1.f + expf(-h));
}

// async 16B global->LDS (per-lane global src; LDS dest = wave base + lane*16)
__device__ __forceinline__ void gll16(const void* g, void* l) {
    __builtin_amdgcn_global_load_lds(
        (const __attribute__((address_space(1))) unsigned int*)g,
        (__attribute__((address_space(3))) unsigned int*)l, 16, 0, 0);
}

// split fp32 -> bf16 hi (truncate) + bf16 lo (truncated residual)
__device__ __forceinline__ void pack_split8(const float f[8], unsigned short* dh, unsigned short* dl) {
    unsigned hb[8], lb[8];
#pragma unroll
    for (int i = 0; i < 8; ++i) {
        unsigned b = __float_as_uint(f[i]);
        float hf = __uint_as_float(b & 0xFFFF0000u);
        float r = f[i] - hf;
        hb[i] = b >> 16;
        lb[i] = __float_as_uint(r) >> 16;
    }
    uint4 hv, lv;
    hv.x = hb[0] | (hb[1] << 16); hv.y = hb[2] | (hb[3] << 16);
    hv.z = hb[4] | (hb[5] << 16); hv.w = hb[6] | (hb[7] << 16);
    lv.x = lb[0] | (lb[1] << 16); lv.y = lb[2] | (lb[3] << 16);
    lv.z = lb[4] | (lb[5] << 16); lv.w = lb[6] | (lb[7] << 16);
    *reinterpret_cast<uint4*>(dh) = hv;
    *reinterpret_cast<uint4*>(dl) = lv;
}

// ================= router =================
__global__ __launch_bounds__(256) void router_kernel(
    const float* __restrict__ x, const float* __restrict__ gw,
    const float* __restrict__ bias,
    int* __restrict__ cnt, float* __restrict__ nsc,
    int* __restrict__ list_p, float* __restrict__ list_w)
{
    const int t = blockIdx.x;
    const int tid = threadIdx.x;

    float part[E_];
#pragma unroll
    for (int e = 0; e < E_; ++e) part[e] = 0.f;

    const float* xr = x + (size_t)t * D_;
    for (int it = 0; it < D_ / 256; ++it) {
        int d = it * 256 + tid;
        float xv = xr[d];
        const float4* g4 = reinterpret_cast<const float4*>(gw + (size_t)d * E_);
#pragma unroll
        for (int q = 0; q < 4; ++q) {
            float4 gv = g4[q];
            part[q * 4 + 0] += xv * gv.x;
            part[q * 4 + 1] += xv * gv.y;
            part[q * 4 + 2] += xv * gv.z;
            part[q * 4 + 3] += xv * gv.w;
        }
    }
#pragma unroll
    for (int e = 0; e < E_; ++e) {
        float v = part[e];
#pragma unroll
        for (int off = 32; off > 0; off >>= 1) v += __shfl_down(v, off);
        part[e] = v;
    }
    __shared__ float red[4 * E_];
    const int wave = tid >> 6, lane = tid & 63;
    if (lane == 0) {
#pragma unroll
        for (int e = 0; e < E_; ++e) red[wave * E_ + e] = part[e];
    }
    __syncthreads();

    __shared__ float sc[E_];
    if (tid < E_) {
        float s = red[0 * E_ + tid] + red[1 * E_ + tid] + red[2 * E_ + tid] + red[3 * E_ + tid];
        s += bias[tid];
        sc[tid] = 1.f / (1.f + expf(-s));
    }
    __syncthreads();

    if (tid == 0) {
        float sum = 0.f;
#pragma unroll
        for (int e = 0; e < E_; ++e) sum += sc[e];
        float den = sum + EPS_;
        float ns[E_];
#pragma unroll
        for (int e = 0; e < E_; ++e) {
            ns[e] = sc[e] / den;
            nsc[(size_t)t * E_ + e] = ns[e];
        }
        bool used[E_];
#pragma unroll
        for (int e = 0; e < E_; ++e) used[e] = false;
        int sel[K_]; float selw[K_]; float wsum = 0.f;
        for (int k = 0; k < K_; ++k) {
            float best = -1.f; int bi = 0;
            for (int e = 0; e < E_; ++e)
                if (!used[e] && ns[e] > best) { best = ns[e]; bi = e; }
            used[bi] = true; sel[k] = bi; selw[k] = best; wsum += best;
        }
        float wden = wsum + EPS_;
        for (int k = 0; k < K_; ++k) {
            int e = sel[k];
            int slot = atomicAdd(&cnt[e], 1);
            list_p[(size_t)e * T_ + slot] = t * K_ + k;
            list_w[(size_t)e * T_ + slot] = selw[k] / wden;
        }
    }
}

// ================= weight conversion =================
// w[e][k][n] fp32 -> per-(e,nt64,ks) 8KB block: 2048 shorts hi ++ 2048 lo.
// run r' = (nf*4+kc)*16+col (nf<4), element j = w[ks*32+kc*8+j][nt*64+nf*16+col]
__global__ __launch_bounds__(256) void conv_w(
    const float* __restrict__ w1, const float* __restrict__ w3, const float* __restrict__ w2,
    unsigned short* __restrict__ d1, unsigned short* __restrict__ d3, unsigned short* __restrict__ d2)
{
    const int b = blockIdx.x;
    const int wsel = b >> 13;          // 8192 blocks per weight
    const int rem = b & 8191;
    const int e = rem >> 9;
    const int rem2 = rem & 511;
    const int nt = rem2 >> 5;
    const int ks = rem2 & 31;
    const int tid = threadIdx.x;

    const float* src = (wsel == 0 ? w1 : wsel == 1 ? w3 : w2)
                     + ((size_t)e * 1024 + ks * 32) * 1024 + nt * 64;
    unsigned short* dst = (wsel == 0 ? d1 : wsel == 1 ? d3 : d2)
                        + ((size_t)(e * 16 + nt) * 32 + ks) * 4096;

    __shared__ float tile[32][65];
    const int r = tid >> 3, c0 = (tid & 7) * 8;
    float4 v0 = *reinterpret_cast<const float4*>(src + (size_t)r * 1024 + c0);
    float4 v1 = *reinterpret_cast<const float4*>(src + (size_t)r * 1024 + c0 + 4);
    tile[r][c0 + 0] = v0.x; tile[r][c0 + 1] = v0.y; tile[r][c0 + 2] = v0.z; tile[r][c0 + 3] = v0.w;
    tile[r][c0 + 4] = v1.x; tile[r][c0 + 5] = v1.y; tile[r][c0 + 6] = v1.z; tile[r][c0 + 7] = v1.w;
    __syncthreads();

    const int nf = tid >> 6, kc = (tid >> 4) & 3, col = tid & 15;
    float f[8];
#pragma unroll
    for (int j = 0; j < 8; ++j) f[j] = tile[kc * 8 + j][nf * 16 + col];
    pack_split8(f, dst + tid * 8, dst + 2048 + tid * 8);
}

// x -> hi/lo planes (row-major [t][d] shorts)
__global__ __launch_bounds__(256) void conv_x(
    const float* __restrict__ x, unsigned short* __restrict__ xhi, unsigned short* __restrict__ xlo)
{
    const size_t i = ((size_t)blockIdx.x * 256 + threadIdx.x) * 8;
    float4 a = *reinterpret_cast<const float4*>(x + i);
    float4 b = *reinterpret_cast<const float4*>(x + i + 4);
    float f[8] = {a.x, a.y, a.z, a.w, b.x, b.y, b.z, b.w};
    pack_split8(f, xhi + i, xlo + i);
}

// ================= GEMM1: a = silu(x@w1)*(x@w3), 2-phase dbuf =================
// BM=128, BN=64, BK=32; 4 waves (2x2); wave tile 64x32.
// LDS: 2x(A 16KB + B 16KB) + meta = 65KB -> 2 blocks/CU.
__global__ __launch_bounds__(256, 2) void gemm1_fast(
    const unsigned short* __restrict__ xhi, const unsigned short* __restrict__ xlo,
    const unsigned short* __restrict__ w1s, const unsigned short* __restrict__ w3s,
    const int* __restrict__ cnt, const int* __restrict__ list_p,
    unsigned short* __restrict__ a_hi, unsigned short* __restrict__ a_lo)
{
    // bijective XCD swizzle over 4096 blocks (4096 % 8 == 0)
    const int bid0 = blockIdx.x;
    const int bid  = (bid0 & 7) * 512 + (bid0 >> 3);
    const int e   = bid >> 8;          // 256 blocks/expert
    const int rem = bid & 255;
    const int mt  = rem >> 4;          // 16 m-tiles
    const int nt  = rem & 15;          // 16 n-tiles of 64
    const int ne  = cnt[e];
    if (mt * 128 >= ne) return;
    const int tid = threadIdx.x;

    __shared__ int ps[128];
    __shared__ int ts[128];
    __shared__ alignas(16) unsigned short Ah[2][4096], Al[2][4096];     // 128x32 each buf
    __shared__ alignas(16) unsigned short B1h[2][2048], B1l[2][2048];   // 32x64 each buf
    __shared__ alignas(16) unsigned short B3h[2][2048], B3l[2][2048];

    if (tid < 128) {
        int slot = mt * 128 + tid;
        if (slot < ne) { int p = list_p[(size_t)e * T_ + slot]; ps[tid] = p; ts[tid] = p >> 2; }
        else           { ps[tid] = -1; ts[tid] = 0; }
    }
    __syncthreads();

    // A gather: runs tid (mf 0..3) and tid+256 (mf 4..7); run R: mf=R>>6, kc=(R>>4)&3, r16=R&15
    const int mf0 = tid >> 6, kc0 = (tid >> 4) & 3, r16 = tid & 15;
    const unsigned short* axh0 = xhi + (size_t)ts[mf0 * 16 + r16] * D_ + kc0 * 8;
    const unsigned short* axl0 = xlo + (size_t)ts[mf0 * 16 + r16] * D_ + kc0 * 8;
    const unsigned short* axh1 = xhi + (size_t)ts[(mf0 + 4) * 16 + r16] * D_ + kc0 * 8;
    const unsigned short* axl1 = xlo + (size_t)ts[(mf0 + 4) * 16 + r16] * D_ + kc0 * 8;

    // B: one 64-col source block per tile; within-block run index == tid
    const unsigned short* b1a = w1s + ((size_t)(e * 16 + nt) * 32) * 4096 + tid * 8;
    const unsigned short* b3a = w3s + ((size_t)(e * 16 + nt) * 32) * 4096 + tid * 8;

    const int w = tid >> 6, l = tid & 63;
    const int wr = w >> 1, wc = w & 1;
    const int lo8 = l * 8;

    auto STAGE = [&](int buf, int ks) {
        const int k0 = ks * 32, ksoff = ks * 4096;
        gll16(axh0 + k0, &Ah[buf][tid * 8]);
        gll16(axh1 + k0, &Ah[buf][(tid + 256) * 8]);
        gll16(axl0 + k0, &Al[buf][tid * 8]);
        gll16(axl1 + k0, &Al[buf][(tid + 256) * 8]);
        gll16(b1a + ksoff,        &B1h[buf][tid * 8]);
        gll16(b1a + ksoff + 2048, &B1l[buf][tid * 8]);
        gll16(b3a + ksoff,        &B3h[buf][tid * 8]);
        gll16(b3a + ksoff + 2048, &B3l[buf][tid * 8]);
    };

    floatx4 acch[4][2], accg[4][2];
#pragma unroll
    for (int i = 0; i < 4; ++i)
#pragma unroll
        for (int j = 0; j < 2; ++j) { acch[i][j] = (floatx4)0.f; accg[i][j] = (floatx4)0.f; }

    STAGE(0, 0);
    __syncthreads();                       // buf0 staged (vmcnt(0)+barrier)

    for (int ks = 0; ks < 32; ++ks) {
        const int cur = ks & 1;
        if (ks < 31) STAGE(cur ^ 1, ks + 1);   // prefetch flies during MFMA below

        short8 ah[4], al[4];
#pragma unroll
        for (int mi = 0; mi < 4; ++mi) {
            int base = (wr * 4 + mi) * 512 + lo8;
            ah[mi] = *reinterpret_cast<const short8*>(&Ah[cur][base]);
            al[mi] = *reinterpret_cast<const short8*>(&Al[cur][base]);
        }
#pragma unroll
        for (int nj = 0; nj < 2; ++nj) {
            int bb = (wc * 2 + nj) * 512 + lo8;
            short8 b1hv = *reinterpret_cast<const short8*>(&B1h[cur][bb]);
            short8 b1lv = *reinterpret_cast<const short8*>(&B1l[cur][bb]);
            short8 b3hv = *reinterpret_cast<const short8*>(&B3h[cur][bb]);
            short8 b3lv = *reinterpret_cast<const short8*>(&B3l[cur][bb]);
#pragma unroll
            for (int mi = 0; mi < 4; ++mi) {
                acch[mi][nj] = MFMA16(ah[mi], b1hv, acch[mi][nj]);
                acch[mi][nj] = MFMA16(al[mi], b1hv, acch[mi][nj]);
                acch[mi][nj] = MFMA16(ah[mi], b1lv, acch[mi][nj]);
                accg[mi][nj] = MFMA16(ah[mi], b3hv, accg[mi][nj]);
                accg[mi][nj] = MFMA16(al[mi], b3hv, accg[mi][nj]);
                accg[mi][nj] = MFMA16(ah[mi], b3lv, accg[mi][nj]);
            }
        }
        __syncthreads();   // drains prefetch (post-compute -> cheap) + read/write fence
    }

    // epilogue: C/D map col=l&15, row=(l>>4)*4+r
    const int g4 = (l >> 4) * 4;
#pragma unroll
    for (int mi = 0; mi < 4; ++mi) {
#pragma unroll
        for (int r = 0; r < 4; ++r) {
            int m = wr * 64 + mi * 16 + g4 + r;
            int p = ps[m];
            if (p < 0) continue;
            size_t ro = (size_t)p * H_ + nt * 64 + wc * 32 + (l & 15);
#pragma unroll
            for (int nj = 0; nj < 2; ++nj) {
                float h = acch[mi][nj][r];
                float g = accg[mi][nj][r];
                float a = silu_f(h) * g;
                unsigned b = __float_as_uint(a);
                float rr = a - __uint_as_float(b & 0xFFFF0000u);
                a_hi[ro + nj * 16] = (unsigned short)(b >> 16);
                a_lo[ro + nj * 16] = (unsigned short)(__float_as_uint(rr) >> 16);
            }
        }
    }
}

// ================= GEMM2: out[t] += wt * (a[p] @ w2[e]), 2-phase dbuf =================
// LDS: 2x(A 16KB + B 8KB) + meta = 49KB -> 3 blocks/CU.
__global__ __launch_bounds__(256, 3) void gemm2_fast(
    const unsigned short* __restrict__ a_hi, const unsigned short* __restrict__ a_lo,
    const unsigned short* __restrict__ w2s, const int* __restrict__ cnt,
    const int* __restrict__ list_p, const float* __restrict__ list_w,
    float* __restrict__ out)
{
    const int bid0 = blockIdx.x;
    const int bid  = (bid0 & 7) * 512 + (bid0 >> 3);
    const int e   = bid >> 8;
    const int rem = bid & 255;
    const int mt  = rem >> 4;
    const int nt  = rem & 15;
    const int ne  = cnt[e];
    if (mt * 128 >= ne) return;
    const int tid = threadIdx.x;

    __shared__ int   ps[128];
    __shared__ float wts[128];
    __shared__ alignas(16) unsigned short Ahs[2][4096], Als[2][4096];
    __shared__ alignas(16) unsigned short Bh[2][2048], Bl[2][2048];

    if (tid < 128) {
        int slot = mt * 128 + tid;
        if (slot < ne) {
            int p = list_p[(size_t)e * T_ + slot];
            ps[tid] = p; wts[tid] = list_w[(size_t)e * T_ + slot];
        } else { ps[tid] = -1; wts[tid] = 0.f; }
    }
    __syncthreads();

    const int mf0 = tid >> 6, kc0 = (tid >> 4) & 3, r16 = tid & 15;
    int p0 = ps[mf0 * 16 + r16];       if (p0 < 0) p0 = 0;
    int p1 = ps[(mf0 + 4) * 16 + r16]; if (p1 < 0) p1 = 0;
    const unsigned short* aah0 = a_hi + (size_t)p0 * H_ + kc0 * 8;
    const unsigned short* aal0 = a_lo + (size_t)p0 * H_ + kc0 * 8;
    const unsigned short* aah1 = a_hi + (size_t)p1 * H_ + kc0 * 8;
    const unsigned short* aal1 = a_lo + (size_t)p1 * H_ + kc0 * 8;

    const unsigned short* b2a = w2s + ((size_t)(e * 16 + nt) * 32) * 4096 + tid * 8;

    const int w = tid >> 6, l = tid & 63;
    const int wr = w >> 1, wc = w & 1;
    const int lo8 = l * 8;

    auto STAGE = [&](int buf, int ks) {
        const int k0 = ks * 32, ksoff = ks * 4096;
        gll16(aah0 + k0, &Ahs[buf][tid * 8]);
        gll16(aah1 + k0, &Ahs[buf][(tid + 256) * 8]);
        gll16(aal0 + k0, &Als[buf][tid * 8]);
        gll16(aal1 + k0, &Als[buf][(tid + 256) * 8]);
        gll16(b2a + ksoff,        &Bh[buf][tid * 8]);
        gll16(b2a + ksoff + 2048, &Bl[buf][tid * 8]);
    };

    floatx4 acc[4][2];
#pragma unroll
    for (int i = 0; i < 4; ++i)
#pragma unroll
        for (int j = 0; j < 2; ++j) acc[i][j] = (floatx4)0.f;

    STAGE(0, 0);
    __syncthreads();

    for (int ks = 0; ks < 32; ++ks) {
        const int cur = ks & 1;
        if (ks < 31) STAGE(cur ^ 1, ks + 1);

        short8 ah[4], al[4];
#pragma unroll
        for (int mi = 0; mi < 4; ++mi) {
            int base = (wr * 4 + mi) * 512 + lo8;
            ah[mi] = *reinterpret_cast<const short8*>(&Ahs[cur][base]);
            al[mi] = *reinterpret_cast<const short8*>(&Als[cur][base]);
        }
#pragma unroll
        for (int nj = 0; nj < 2; ++nj) {
            int bb = (wc * 2 + nj) * 512 + lo8;
            short8 bhv = *reinterpret_cast<const short8*>(&Bh[cur][bb]);
            short8 blv = *reinterpret_cast<const short8*>(&Bl[cur][bb]);
#pragma unroll
            for (int mi = 0; mi < 4; ++mi) {
                acc[mi][nj] = MFMA16(ah[mi], bhv, acc[mi][nj]);
                acc[mi][nj] = MFMA16(al[mi], bhv, acc[mi][nj]);
                acc[mi][nj] = MFMA16(ah[mi], blv, acc[mi][nj]);
            }
        }
        __syncthreads();
    }

    const int g4 = (l >> 4) * 4;
#pragma unroll
    for (int mi = 0; mi < 4; ++mi) {
#pragma unroll
        for (int r = 0; r < 4; ++r) {
            int m = wr * 64 + mi * 16 + g4 + r;
            int p = ps[m];
            if (p < 0) continue;
            int t = p >> 2;
            float wt = wts[m];
            float* dst = out + (size_t)t * D_ + nt * 64 + wc * 32 + (l & 15);
#pragma unroll
            for (int nj = 0; nj < 2; ++nj)
                atomicAdd(dst + nj * 16, wt * acc[mi][nj][r]);
        }
    }
}

// ================= lb_loss =================
__global__ __launch_bounds__(256) void lb_kernel(
    const float* __restrict__ nsc, const int* __restrict__ cnt, float* __restrict__ out)
{
    const int tid = threadIdx.x;
    float part[E_];
#pragma unroll
    for (int e = 0; e < E_; ++e) part[e] = 0.f;
    for (int t = tid; t < T_; t += 256) {
        const float4* r4 = reinterpret_cast<const float4*>(nsc + (size_t)t * E_);
#pragma unroll
        for (int q = 0; q < 4; ++q) {
            float4 v = r4[q];
            part[q * 4 + 0] += v.x; part[q * 4 + 1] += v.y;
            part[q * 4 + 2] += v.z; part[q * 4 + 3] += v.w;
        }
    }
#pragma unroll
    for (int e = 0; e < E_; ++e) {
        float v = part[e];
#pragma unroll
        for (int off = 32; off > 0; off >>= 1) v += __shfl_down(v, off);
        part[e] = v;
    }
    __shared__ float red[4 * E_];
    const int wave = tid >> 6, lane = tid & 63;
    if (lane == 0) {
#pragma unroll
        for (int e = 0; e < E_; ++e) red[wave * E_ + e] = part[e];
    }
    __syncthreads();
    if (tid == 0) {
        float lb = 0.f;
        for (int e = 0; e < E_; ++e) {
            float s = red[0 * E_ + e] + red[1 * E_ + e] + red[2 * E_ + e] + red[3 * E_ + e];
            lb += ((float)cnt[e] / (float)T_) * (s / (float)T_);
        }
        out[(size_t)T_ * D_] = (float)E_ * lb;
    }
}

// ================= launch =================
extern "C" void kernel_launch(void* const* d_in, const int* in_sizes, int n_in,
                              void* d_out, int out_size, void* d_ws, size_t ws_size,
                              hipStream_t stream)
{
    const float* x    = (const float*)d_in[0];
    const float* gw   = (const float*)d_in[1];
    const float* bias = (const float*)d_in[2];
    const float* w1   = (const float*)d_in[3];
    const float* w3   = (const float*)d_in[4];
    const float* w2   = (const float*)d_in[5];
    float* out = (float*)d_out;
    char*  ws  = (char*)d_ws;

    int*   cnt    = (int*)  (ws + FWS_CNT);
    int*   list_p = (int*)  (ws + FWS_LISTP);
    float* list_w = (float*)(ws + FWS_LISTW);
    float* nsc    = (float*)(ws + FWS_NSC);
    unsigned short* xhi  = (unsigned short*)(ws + FWS_XHI);
    unsigned short* xlo  = (unsigned short*)(ws + FWS_XLO);
    unsigned short* a_hi = (unsigned short*)(ws + FWS_AHI);
    unsigned short* a_lo = (unsigned short*)(ws + FWS_ALO);
    unsigned short* w1s  = (unsigned short*)(ws + FWS_W1S);
    unsigned short* w3s  = (unsigned short*)(ws + FWS_W3S);
    unsigned short* w2s  = (unsigned short*)(ws + FWS_W2S);

    hipMemsetAsync(d_out, 0, (size_t)out_size * sizeof(float), stream);
    hipMemsetAsync(ws, 0, 256, stream);   // cnt

    conv_w<<<3 * 8192, 256, 0, stream>>>(w1, w3, w2, w1s, w3s, w2s);
    conv_x<<<T_ * D_ / (256 * 8), 256, 0, stream>>>(x, xhi, xlo);
    router_kernel<<<T_, 256, 0, stream>>>(x, gw, bias, cnt, nsc, list_p, list_w);
    gemm1_fast<<<E_ * FMT * FNT, 256, 0, stream>>>(xhi, xlo, w1s, w3s, cnt, list_p, a_hi, a_lo);
    gemm2_fast<<<E_ * FMT * FNT, 256, 0, stream>>>(a_hi, a_lo, w2s, cnt, list_p, list_w, out);
    lb_kernel<<<1, 256, 0, stream>>>(nsc, cnt, out);
}

// Round 11
// 560.190 us; speedup vs baseline: 1.1929x; 1.1929x over previous
//
#include <hip/hip_runtime.h>
#include <math.h>

// ---------------- problem constants ----------------
constexpr int T_ = 2048;   // tokens (B*S)
constexpr int D_ = 1024;   // model dim
constexpr int E_ = 16;     // experts
constexpr int H_ = 1024;   // expert hidden
constexpr int K_ = 4;      // top-k
constexpr float EPS_ = 1e-6f;

// ---------------- workspace layout (bytes) ----------------
constexpr size_t FWS_CNT   = 0;                                   // E ints
constexpr size_t FWS_LISTP = 256;
constexpr size_t FWS_LISTW = FWS_LISTP + (size_t)E_ * T_ * 4;
constexpr size_t FWS_NSC   = FWS_LISTW + (size_t)E_ * T_ * 4;
constexpr size_t FWS_XHI   = FWS_NSC  + (size_t)T_ * E_ * 4;      // T*D shorts
constexpr size_t FWS_XLO   = FWS_XHI  + (size_t)T_ * D_ * 2;
constexpr size_t FWS_AHI   = FWS_XLO  + (size_t)T_ * D_ * 2;      // T*K*H shorts
constexpr size_t FWS_ALO   = FWS_AHI  + (size_t)T_ * K_ * H_ * 2;
constexpr size_t FWS_W1S   = FWS_ALO  + (size_t)T_ * K_ * H_ * 2; // swizzled hi/lo
constexpr size_t FWS_W3S   = FWS_W1S  + (size_t)E_ * D_ * H_ * 4;
constexpr size_t FWS_W2S   = FWS_W3S  + (size_t)E_ * D_ * H_ * 4;
constexpr size_t FWS_NEED  = FWS_W2S  + (size_t)E_ * H_ * D_ * 4; // ~232 MB (fits)

using short8  = __attribute__((ext_vector_type(8))) short;
using floatx4 = __attribute__((ext_vector_type(4))) float;

#define MFMA16(a, b, c) __builtin_amdgcn_mfma_f32_16x16x32_bf16((a), (b), (c), 0, 0, 0)

__device__ __forceinline__ float silu_f(float h) {
    return h / (1.f + expf(-h));
}

// async 16B global->LDS (per-lane global src; LDS dest = wave base + lane*16)
__device__ __forceinline__ void gll16(const void* g, void* l) {
    __builtin_amdgcn_global_load_lds(
        (const __attribute__((address_space(1))) unsigned int*)g,
        (__attribute__((address_space(3))) unsigned int*)l, 16, 0, 0);
}

// split fp32 -> bf16 hi (truncate) + bf16 lo (truncated residual)
__device__ __forceinline__ void pack_split8(const float f[8], unsigned short* dh, unsigned short* dl) {
    unsigned hb[8], lb[8];
#pragma unroll
    for (int i = 0; i < 8; ++i) {
        unsigned b = __float_as_uint(f[i]);
        float hf = __uint_as_float(b & 0xFFFF0000u);
        float r = f[i] - hf;
        hb[i] = b >> 16;
        lb[i] = __float_as_uint(r) >> 16;
    }
    uint4 hv, lv;
    hv.x = hb[0] | (hb[1] << 16); hv.y = hb[2] | (hb[3] << 16);
    hv.z = hb[4] | (hb[5] << 16); hv.w = hb[6] | (hb[7] << 16);
    lv.x = lb[0] | (lb[1] << 16); lv.y = lb[2] | (lb[3] << 16);
    lv.z = lb[4] | (lb[5] << 16); lv.w = lb[6] | (lb[7] << 16);
    *reinterpret_cast<uint4*>(dh) = hv;
    *reinterpret_cast<uint4*>(dl) = lv;
}

// ================= fused pre-kernel: conv_w ++ conv_x ++ router =================
// blocks [0,24576): weight conversion; [24576,25600): x->hi/lo; [25600,27648): router
__global__ __launch_bounds__(256) void pre_kernel(
    const float* __restrict__ w1, const float* __restrict__ w3, const float* __restrict__ w2,
    unsigned short* __restrict__ d1, unsigned short* __restrict__ d3, unsigned short* __restrict__ d2,
    const float* __restrict__ x, unsigned short* __restrict__ xhi, unsigned short* __restrict__ xlo,
    const float* __restrict__ gw, const float* __restrict__ bias,
    int* __restrict__ cnt, float* __restrict__ nsc,
    int* __restrict__ list_p, float* __restrict__ list_w)
{
    const int b = blockIdx.x;
    const int tid = threadIdx.x;
    __shared__ float tile[32][65];          // conv_w transpose tile (also covers router smem)
    __shared__ float red[4 * E_];
    __shared__ float sc[E_];

    if (b < 24576) {
        // ---- conv_w: w[e][k][n] -> per-(e,nt64,ks) 8KB block (2048 hi ++ 2048 lo) ----
        const int wsel = b >> 13;
        const int rem = b & 8191;
        const int e = rem >> 9;
        const int rem2 = rem & 511;
        const int nt = rem2 >> 5;
        const int ks = rem2 & 31;

        const float* src = (wsel == 0 ? w1 : wsel == 1 ? w3 : w2)
                         + ((size_t)e * 1024 + ks * 32) * 1024 + nt * 64;
        unsigned short* dst = (wsel == 0 ? d1 : wsel == 1 ? d3 : d2)
                            + ((size_t)(e * 16 + nt) * 32 + ks) * 4096;

        const int r = tid >> 3, c0 = (tid & 7) * 8;
        float4 v0 = *reinterpret_cast<const float4*>(src + (size_t)r * 1024 + c0);
        float4 v1 = *reinterpret_cast<const float4*>(src + (size_t)r * 1024 + c0 + 4);
        tile[r][c0 + 0] = v0.x; tile[r][c0 + 1] = v0.y; tile[r][c0 + 2] = v0.z; tile[r][c0 + 3] = v0.w;
        tile[r][c0 + 4] = v1.x; tile[r][c0 + 5] = v1.y; tile[r][c0 + 6] = v1.z; tile[r][c0 + 7] = v1.w;
        __syncthreads();

        const int nf = tid >> 6, kc = (tid >> 4) & 3, col = tid & 15;
        float f[8];
#pragma unroll
        for (int j = 0; j < 8; ++j) f[j] = tile[kc * 8 + j][nf * 16 + col];
        pack_split8(f, dst + tid * 8, dst + 2048 + tid * 8);

    } else if (b < 25600) {
        // ---- conv_x: x -> hi/lo planes ----
        const size_t i = ((size_t)(b - 24576) * 256 + tid) * 8;
        float4 a = *reinterpret_cast<const float4*>(x + i);
        float4 bb = *reinterpret_cast<const float4*>(x + i + 4);
        float f[8] = {a.x, a.y, a.z, a.w, bb.x, bb.y, bb.z, bb.w};
        pack_split8(f, xhi + i, xlo + i);

    } else {
        // ---- router: one block per token ----
        const int t = b - 25600;
        float part[E_];
#pragma unroll
        for (int e = 0; e < E_; ++e) part[e] = 0.f;

        const float* xr = x + (size_t)t * D_;
        for (int it = 0; it < D_ / 256; ++it) {
            int d = it * 256 + tid;
            float xv = xr[d];
            const float4* g4 = reinterpret_cast<const float4*>(gw + (size_t)d * E_);
#pragma unroll
            for (int q = 0; q < 4; ++q) {
                float4 gv = g4[q];
                part[q * 4 + 0] += xv * gv.x;
                part[q * 4 + 1] += xv * gv.y;
                part[q * 4 + 2] += xv * gv.z;
                part[q * 4 + 3] += xv * gv.w;
            }
        }
#pragma unroll
        for (int e = 0; e < E_; ++e) {
            float v = part[e];
#pragma unroll
            for (int off = 32; off > 0; off >>= 1) v += __shfl_down(v, off);
            part[e] = v;
        }
        const int wave = tid >> 6, lane = tid & 63;
        if (lane == 0) {
#pragma unroll
            for (int e = 0; e < E_; ++e) red[wave * E_ + e] = part[e];
        }
        __syncthreads();

        if (tid < E_) {
            float s = red[0 * E_ + tid] + red[1 * E_ + tid] + red[2 * E_ + tid] + red[3 * E_ + tid];
            s += bias[tid];
            sc[tid] = 1.f / (1.f + expf(-s));
        }
        __syncthreads();

        if (tid == 0) {
            float sum = 0.f;
#pragma unroll
            for (int e = 0; e < E_; ++e) sum += sc[e];
            float den = sum + EPS_;
            float ns[E_];
#pragma unroll
            for (int e = 0; e < E_; ++e) {
                ns[e] = sc[e] / den;
                nsc[(size_t)t * E_ + e] = ns[e];
            }
            bool used[E_];
#pragma unroll
            for (int e = 0; e < E_; ++e) used[e] = false;
            int sel[K_]; float selw[K_]; float wsum = 0.f;
            for (int k = 0; k < K_; ++k) {
                float best = -1.f; int bi = 0;
                for (int e = 0; e < E_; ++e)
                    if (!used[e] && ns[e] > best) { best = ns[e]; bi = e; }
                used[bi] = true; sel[k] = bi; selw[k] = best; wsum += best;
            }
            float wden = wsum + EPS_;
            for (int k = 0; k < K_; ++k) {
                int e = sel[k];
                int slot = atomicAdd(&cnt[e], 1);
                list_p[(size_t)e * T_ + slot] = t * K_ + k;
                list_w[(size_t)e * T_ + slot] = selw[k] / wden;
            }
        }
    }
}

// ================= GEMM1 (r5-proven): a = silu(x@w1)*(x@w3) =================
// BM=128, BN=64, BK=32; 4 waves; wave tile 64x32; single-buffered gll16 staging.
__global__ __launch_bounds__(256, 4) void gemm1_fast(
    const unsigned short* __restrict__ xhi, const unsigned short* __restrict__ xlo,
    const unsigned short* __restrict__ w1s, const unsigned short* __restrict__ w3s,
    const int* __restrict__ cnt, const int* __restrict__ list_p,
    unsigned short* __restrict__ a_hi, unsigned short* __restrict__ a_lo)
{
    const int bid = blockIdx.x;
    const int e   = bid >> 8;
    const int rem = bid & 255;
    const int mt  = rem >> 4;
    const int nt  = rem & 15;
    const int ne  = cnt[e];
    if (mt * 128 >= ne) return;
    const int tid = threadIdx.x;

    __shared__ int ps[128];
    __shared__ int ts[128];
    __shared__ alignas(16) unsigned short Ah[4096], Al[4096];       // 128x32
    __shared__ alignas(16) unsigned short B1h[2048], B1l[2048];     // 32x64
    __shared__ alignas(16) unsigned short B3h[2048], B3l[2048];

    if (tid < 128) {
        int slot = mt * 128 + tid;
        if (slot < ne) { int p = list_p[(size_t)e * T_ + slot]; ps[tid] = p; ts[tid] = p >> 2; }
        else           { ps[tid] = -1; ts[tid] = 0; }
    }
    __syncthreads();

    const int mf0 = tid >> 6, kc0 = (tid >> 4) & 3, r16 = tid & 15;
    const unsigned short* axh0 = xhi + (size_t)ts[mf0 * 16 + r16] * D_ + kc0 * 8;
    const unsigned short* axl0 = xlo + (size_t)ts[mf0 * 16 + r16] * D_ + kc0 * 8;
    const unsigned short* axh1 = xhi + (size_t)ts[(mf0 + 4) * 16 + r16] * D_ + kc0 * 8;
    const unsigned short* axl1 = xlo + (size_t)ts[(mf0 + 4) * 16 + r16] * D_ + kc0 * 8;

    const unsigned short* b1base = w1s + ((size_t)(e * 16 + nt) * 32) * 4096;
    const unsigned short* b3base = w3s + ((size_t)(e * 16 + nt) * 32) * 4096;

    const int w = tid >> 6, l = tid & 63;
    const int wr = w >> 1, wc = w & 1;
    const int lo8 = l * 8;

    floatx4 acch[4][2], accg[4][2];
#pragma unroll
    for (int i = 0; i < 4; ++i)
#pragma unroll
        for (int j = 0; j < 2; ++j) { acch[i][j] = (floatx4)0.f; accg[i][j] = (floatx4)0.f; }

    for (int k0 = 0; k0 < D_; k0 += 32) {
        const unsigned short* b1 = b1base + (size_t)(k0 >> 5) * 4096;
        const unsigned short* b3 = b3base + (size_t)(k0 >> 5) * 4096;
        gll16(axh0 + k0, Ah + tid * 8);
        gll16(axh1 + k0, Ah + (tid + 256) * 8);
        gll16(axl0 + k0, Al + tid * 8);
        gll16(axl1 + k0, Al + (tid + 256) * 8);
        gll16(b1 + tid * 8,        B1h + tid * 8);
        gll16(b1 + 2048 + tid * 8, B1l + tid * 8);
        gll16(b3 + tid * 8,        B3h + tid * 8);
        gll16(b3 + 2048 + tid * 8, B3l + tid * 8);
        __syncthreads();

        short8 ah[4], al[4];
#pragma unroll
        for (int mi = 0; mi < 4; ++mi) {
            int base = (wr * 4 + mi) * 512 + lo8;
            ah[mi] = *reinterpret_cast<const short8*>(Ah + base);
            al[mi] = *reinterpret_cast<const short8*>(Al + base);
        }
#pragma unroll
        for (int nj = 0; nj < 2; ++nj) {
            int bb = (wc * 2 + nj) * 512 + lo8;
            short8 b1hv = *reinterpret_cast<const short8*>(B1h + bb);
            short8 b1lv = *reinterpret_cast<const short8*>(B1l + bb);
            short8 b3hv = *reinterpret_cast<const short8*>(B3h + bb);
            short8 b3lv = *reinterpret_cast<const short8*>(B3l + bb);
#pragma unroll
            for (int mi = 0; mi < 4; ++mi) {
                acch[mi][nj] = MFMA16(ah[mi], b1hv, acch[mi][nj]);
                acch[mi][nj] = MFMA16(al[mi], b1hv, acch[mi][nj]);
                acch[mi][nj] = MFMA16(ah[mi], b1lv, acch[mi][nj]);
                accg[mi][nj] = MFMA16(ah[mi], b3hv, accg[mi][nj]);
                accg[mi][nj] = MFMA16(al[mi], b3hv, accg[mi][nj]);
                accg[mi][nj] = MFMA16(ah[mi], b3lv, accg[mi][nj]);
            }
        }
        __syncthreads();
    }

    const int g4 = (l >> 4) * 4;
#pragma unroll
    for (int mi = 0; mi < 4; ++mi) {
#pragma unroll
        for (int r = 0; r < 4; ++r) {
            int m = wr * 64 + mi * 16 + g4 + r;
            int p = ps[m];
            if (p < 0) continue;
            size_t ro = (size_t)p * H_ + nt * 64 + wc * 32 + (l & 15);
#pragma unroll
            for (int nj = 0; nj < 2; ++nj) {
                float h = acch[mi][nj][r];
                float g = accg[mi][nj][r];
                float a = silu_f(h) * g;
                unsigned b = __float_as_uint(a);
                float rr = a - __uint_as_float(b & 0xFFFF0000u);
                a_hi[ro + nj * 16] = (unsigned short)(b >> 16);
                a_lo[ro + nj * 16] = (unsigned short)(__float_as_uint(rr) >> 16);
            }
        }
    }
}

// ================= GEMM2 (r7-proven) + folded lb block =================
// BM=128, BN=128, single-buffered, XCD swizzle; block 2048 computes lb_loss.
__global__ __launch_bounds__(256, 3) void gemm2_fast(
    const unsigned short* __restrict__ a_hi, const unsigned short* __restrict__ a_lo,
    const unsigned short* __restrict__ w2s, const int* __restrict__ cnt,
    const int* __restrict__ list_p, const float* __restrict__ list_w,
    const float* __restrict__ nsc, float* __restrict__ out)
{
    const int tid = threadIdx.x;

    if (blockIdx.x == 2048) {
        // ---- lb_loss ----
        float part[E_];
#pragma unroll
        for (int e = 0; e < E_; ++e) part[e] = 0.f;
        for (int t = tid; t < T_; t += 256) {
            const float4* r4 = reinterpret_cast<const float4*>(nsc + (size_t)t * E_);
#pragma unroll
            for (int q = 0; q < 4; ++q) {
                float4 v = r4[q];
                part[q * 4 + 0] += v.x; part[q * 4 + 1] += v.y;
                part[q * 4 + 2] += v.z; part[q * 4 + 3] += v.w;
            }
        }
#pragma unroll
        for (int e = 0; e < E_; ++e) {
            float v = part[e];
#pragma unroll
            for (int off = 32; off > 0; off >>= 1) v += __shfl_down(v, off);
            part[e] = v;
        }
        __shared__ float red[4 * E_];
        const int wave = tid >> 6, lane = tid & 63;
        if (lane == 0) {
#pragma unroll
            for (int e = 0; e < E_; ++e) red[wave * E_ + e] = part[e];
        }
        __syncthreads();
        if (tid == 0) {
            float lb = 0.f;
            for (int e = 0; e < E_; ++e) {
                float s = red[0 * E_ + e] + red[1 * E_ + e] + red[2 * E_ + e] + red[3 * E_ + e];
                lb += ((float)cnt[e] / (float)T_) * (s / (float)T_);
            }
            out[(size_t)T_ * D_] = (float)E_ * lb;
        }
        return;
    }

    const int bid0 = blockIdx.x;
    const int bid  = (bid0 & 7) * 256 + (bid0 >> 3);   // bijective XCD swizzle over 2048
    const int e   = bid >> 7;
    const int rem = bid & 127;
    const int mt  = rem >> 3;
    const int ntb = rem & 7;
    const int ne  = cnt[e];
    if (mt * 128 >= ne) return;

    __shared__ int   ps[128];
    __shared__ float wts[128];
    __shared__ alignas(16) unsigned short Ahs[4096], Als[4096];
    __shared__ alignas(16) unsigned short Bh[4096], Bl[4096];

    if (tid < 128) {
        int slot = mt * 128 + tid;
        if (slot < ne) {
            int p = list_p[(size_t)e * T_ + slot];
            ps[tid] = p; wts[tid] = list_w[(size_t)e * T_ + slot];
        } else { ps[tid] = -1; wts[tid] = 0.f; }
    }
    __syncthreads();

    const int mf0 = tid >> 6, kc0 = (tid >> 4) & 3, r16 = tid & 15;
    int p0 = ps[mf0 * 16 + r16];      if (p0 < 0) p0 = 0;
    int p1 = ps[mf0 * 16 + 64 + r16]; if (p1 < 0) p1 = 0;
    const unsigned short* aah0 = a_hi + (size_t)p0 * H_ + kc0 * 8;
    const unsigned short* aal0 = a_lo + (size_t)p0 * H_ + kc0 * 8;
    const unsigned short* aah1 = a_hi + (size_t)p1 * H_ + kc0 * 8;
    const unsigned short* aal1 = a_lo + (size_t)p1 * H_ + kc0 * 8;

    const unsigned short* b2a = w2s + ((size_t)(e * 16 + ntb * 2)     * 32) * 4096 + tid * 8;
    const unsigned short* b2b = w2s + ((size_t)(e * 16 + ntb * 2 + 1) * 32) * 4096 + tid * 8;

    const int w = tid >> 6, l = tid & 63;
    const int wr = w >> 1, wc = w & 1;
    const int lo8 = l * 8;

    floatx4 acc[4][4];
#pragma unroll
    for (int i = 0; i < 4; ++i)
#pragma unroll
        for (int j = 0; j < 4; ++j) acc[i][j] = (floatx4)0.f;

    for (int k0 = 0; k0 < H_; k0 += 32) {
        const int ksoff = (k0 >> 5) * 4096;
        gll16(aah0 + k0, Ahs + tid * 8);
        gll16(aah1 + k0, Ahs + (tid + 256) * 8);
        gll16(aal0 + k0, Als + tid * 8);
        gll16(aal1 + k0, Als + (tid + 256) * 8);
        gll16(b2a + ksoff,        Bh + tid * 8);
        gll16(b2b + ksoff,        Bh + (tid + 256) * 8);
        gll16(b2a + ksoff + 2048, Bl + tid * 8);
        gll16(b2b + ksoff + 2048, Bl + (tid + 256) * 8);
        __syncthreads();

        short8 ah[4], al[4];
#pragma unroll
        for (int mi = 0; mi < 4; ++mi) {
            int base = (wr * 4 + mi) * 512 + lo8;
            ah[mi] = *reinterpret_cast<const short8*>(Ahs + base);
            al[mi] = *reinterpret_cast<const short8*>(Als + base);
        }
#pragma unroll
        for (int nj = 0; nj < 4; ++nj) {
            int bb = (wc * 4 + nj) * 512 + lo8;
            short8 bhv = *reinterpret_cast<const short8*>(Bh + bb);
            short8 blv = *reinterpret_cast<const short8*>(Bl + bb);
#pragma unroll
            for (int mi = 0; mi < 4; ++mi) {
                acc[mi][nj] = MFMA16(ah[mi], bhv, acc[mi][nj]);
                acc[mi][nj] = MFMA16(al[mi], bhv, acc[mi][nj]);
                acc[mi][nj] = MFMA16(ah[mi], blv, acc[mi][nj]);
            }
        }
        __syncthreads();
    }

    const int g4 = (l >> 4) * 4;
#pragma unroll
    for (int mi = 0; mi < 4; ++mi) {
#pragma unroll
        for (int r = 0; r < 4; ++r) {
            int m = wr * 64 + mi * 16 + g4 + r;
            int p = ps[m];
            if (p < 0) continue;
            int t = p >> 2;
            float wt = wts[m];
            float* dst = out + (size_t)t * D_ + ntb * 128 + wc * 64 + (l & 15);
#pragma unroll
            for (int nj = 0; nj < 4; ++nj)
                atomicAdd(dst + nj * 16, wt * acc[mi][nj][r]);
        }
    }
}

// ================= launch =================
extern "C" void kernel_launch(void* const* d_in, const int* in_sizes, int n_in,
                              void* d_out, int out_size, void* d_ws, size_t ws_size,
                              hipStream_t stream)
{
    const float* x    = (const float*)d_in[0];
    const float* gw   = (const float*)d_in[1];
    const float* bias = (const float*)d_in[2];
    const float* w1   = (const float*)d_in[3];
    const float* w3   = (const float*)d_in[4];
    const float* w2   = (const float*)d_in[5];
    float* out = (float*)d_out;
    char*  ws  = (char*)d_ws;

    int*   cnt    = (int*)  (ws + FWS_CNT);
    int*   list_p = (int*)  (ws + FWS_LISTP);
    float* list_w = (float*)(ws + FWS_LISTW);
    float* nsc    = (float*)(ws + FWS_NSC);
    unsigned short* xhi  = (unsigned short*)(ws + FWS_XHI);
    unsigned short* xlo  = (unsigned short*)(ws + FWS_XLO);
    unsigned short* a_hi = (unsigned short*)(ws + FWS_AHI);
    unsigned short* a_lo = (unsigned short*)(ws + FWS_ALO);
    unsigned short* w1s  = (unsigned short*)(ws + FWS_W1S);
    unsigned short* w3s  = (unsigned short*)(ws + FWS_W3S);
    unsigned short* w2s  = (unsigned short*)(ws + FWS_W2S);

    hipMemsetAsync(d_out, 0, (size_t)out_size * sizeof(float), stream);
    hipMemsetAsync(ws, 0, 256, stream);   // cnt

    pre_kernel<<<27648, 256, 0, stream>>>(w1, w3, w2, w1s, w3s, w2s,
                                          x, xhi, xlo, gw, bias,
                                          cnt, nsc, list_p, list_w);
    gemm1_fast<<<4096, 256, 0, stream>>>(xhi, xlo, w1s, w3s, cnt, list_p, a_hi, a_lo);
    gemm2_fast<<<2049, 256, 0, stream>>>(a_hi, a_lo, w2s, cnt, list_p, list_w, nsc, out);
}

// Round 13
// 524.210 us; speedup vs baseline: 1.2748x; 1.0686x over previous
//
#include <hip/hip_runtime.h>
#include <math.h>

// ---------------- problem constants ----------------
constexpr int T_ = 2048;   // tokens (B*S)
constexpr int D_ = 1024;   // model dim
constexpr int E_ = 16;     // experts
constexpr int H_ = 1024;   // expert hidden
constexpr int K_ = 4;      // top-k
constexpr float EPS_ = 1e-6f;

// ---------------- workspace layout (bytes) ----------------
constexpr size_t FWS_CNT   = 0;                                   // E ints
constexpr size_t FWS_LISTP = 256;
constexpr size_t FWS_LISTW = FWS_LISTP + (size_t)E_ * T_ * 4;
constexpr size_t FWS_NSC   = FWS_LISTW + (size_t)E_ * T_ * 4;
constexpr size_t FWS_XHI   = FWS_NSC  + (size_t)T_ * E_ * 4;      // T*D shorts
constexpr size_t FWS_XLO   = FWS_XHI  + (size_t)T_ * D_ * 2;
constexpr size_t FWS_AHI   = FWS_XLO  + (size_t)T_ * D_ * 2;      // T*K*H shorts
constexpr size_t FWS_ALO   = FWS_AHI  + (size_t)T_ * K_ * H_ * 2;
constexpr size_t FWS_W1S   = FWS_ALO  + (size_t)T_ * K_ * H_ * 2; // swizzled hi/lo
constexpr size_t FWS_W3S   = FWS_W1S  + (size_t)E_ * D_ * H_ * 4;
constexpr size_t FWS_W2S   = FWS_W3S  + (size_t)E_ * D_ * H_ * 4;
constexpr size_t FWS_NEED  = FWS_W2S  + (size_t)E_ * H_ * D_ * 4; // ~232 MB (fits)

using short8  = __attribute__((ext_vector_type(8))) short;
using floatx4 = __attribute__((ext_vector_type(4))) float;

#define MFMA16(a, b, c) __builtin_amdgcn_mfma_f32_16x16x32_bf16((a), (b), (c), 0, 0, 0)

__device__ __forceinline__ float silu_f(float h) {
    return h / (1.f + expf(-h));
}

// async 16B global->LDS (per-lane global src; LDS dest = wave base + lane*16)
__device__ __forceinline__ void gll16(const void* g, void* l) {
    __builtin_amdgcn_global_load_lds(
        (const __attribute__((address_space(1))) unsigned int*)g,
        (__attribute__((address_space(3))) unsigned int*)l, 16, 0, 0);
}

// split fp32 -> bf16 hi (truncate) + bf16 lo (truncated residual)
__device__ __forceinline__ void pack_split8(const float f[8], unsigned short* dh, unsigned short* dl) {
    unsigned hb[8], lb[8];
#pragma unroll
    for (int i = 0; i < 8; ++i) {
        unsigned b = __float_as_uint(f[i]);
        float hf = __uint_as_float(b & 0xFFFF0000u);
        float r = f[i] - hf;
        hb[i] = b >> 16;
        lb[i] = __float_as_uint(r) >> 16;
    }
    uint4 hv, lv;
    hv.x = hb[0] | (hb[1] << 16); hv.y = hb[2] | (hb[3] << 16);
    hv.z = hb[4] | (hb[5] << 16); hv.w = hb[6] | (hb[7] << 16);
    lv.x = lb[0] | (lb[1] << 16); lv.y = lb[2] | (lb[3] << 16);
    lv.z = lb[4] | (lb[5] << 16); lv.w = lb[6] | (lb[7] << 16);
    *reinterpret_cast<uint4*>(dh) = hv;
    *reinterpret_cast<uint4*>(dl) = lv;
}

// ================= fused pre-kernel: conv_w strips ++ conv_x ++ router =================
// blocks [0,768): weight-conversion strips (32 k-chunks each, dbuf pipeline);
// [768,1792): x->hi/lo; [1792,3840): router
__global__ __launch_bounds__(256) void pre_kernel(
    const float* __restrict__ w1, const float* __restrict__ w3, const float* __restrict__ w2,
    unsigned short* __restrict__ d1, unsigned short* __restrict__ d3, unsigned short* __restrict__ d2,
    const float* __restrict__ x, unsigned short* __restrict__ xhi, unsigned short* __restrict__ xlo,
    const float* __restrict__ gw, const float* __restrict__ bias,
    int* __restrict__ cnt, float* __restrict__ nsc,
    int* __restrict__ list_p, float* __restrict__ list_w)
{
    const int b = blockIdx.x;
    const int tid = threadIdx.x;
    __shared__ float tile[2][32][65];       // conv_w dbuf transpose tiles (16.6 KB)
    __shared__ float red[4 * E_];
    __shared__ float sc[E_];

    if (b < 768) {
        // ---- conv_w strip: one (wsel, e, nt64) per block; 32 k-chunks pipelined ----
        const int wsel = b >> 8;            // 256 blocks per weight
        const int rem  = b & 255;
        const int e    = rem >> 4;
        const int nt   = rem & 15;

        const float* src = (wsel == 0 ? w1 : wsel == 1 ? w3 : w2)
                         + (size_t)e * 1024 * 1024 + nt * 64;
        unsigned short* dst = (wsel == 0 ? d1 : wsel == 1 ? d3 : d2)
                            + ((size_t)(e * 16 + nt) * 32) * 4096;

        const int r = tid >> 3, c0 = (tid & 7) * 8;                 // staging decode
        const int nf = tid >> 6, kc = (tid >> 4) & 3, col = tid & 15; // pack decode

        float4 ra = *reinterpret_cast<const float4*>(src + (size_t)r * 1024 + c0);
        float4 rb = *reinterpret_cast<const float4*>(src + (size_t)r * 1024 + c0 + 4);

        for (int ks = 0; ks < 32; ++ks) {
            const int cur = ks & 1;
            tile[cur][r][c0 + 0] = ra.x; tile[cur][r][c0 + 1] = ra.y;
            tile[cur][r][c0 + 2] = ra.z; tile[cur][r][c0 + 3] = ra.w;
            tile[cur][r][c0 + 4] = rb.x; tile[cur][r][c0 + 5] = rb.y;
            tile[cur][r][c0 + 6] = rb.z; tile[cur][r][c0 + 7] = rb.w;
            float4 ra2, rb2;
            if (ks < 31) {   // next-chunk loads fly during pack+store below
                const float* s2 = src + (size_t)((ks + 1) * 32 + r) * 1024 + c0;
                ra2 = *reinterpret_cast<const float4*>(s2);
                rb2 = *reinterpret_cast<const float4*>(s2 + 4);
            }
            __syncthreads();   // tile[cur] written by all; also separates prior reads of tile[cur^1]

            float f[8];
#pragma unroll
            for (int j = 0; j < 8; ++j) f[j] = tile[cur][kc * 8 + j][nf * 16 + col];
            unsigned short* dk = dst + (size_t)ks * 4096;
            pack_split8(f, dk + tid * 8, dk + 2048 + tid * 8);

            if (ks < 31) { ra = ra2; rb = rb2; }
        }

    } else if (b < 1792) {
        // ---- conv_x: x -> hi/lo planes ----
        const size_t i = ((size_t)(b - 768) * 256 + tid) * 8;
        float4 a = *reinterpret_cast<const float4*>(x + i);
        float4 bb = *reinterpret_cast<const float4*>(x + i + 4);
        float f[8] = {a.x, a.y, a.z, a.w, bb.x, bb.y, bb.z, bb.w};
        pack_split8(f, xhi + i, xlo + i);

    } else {
        // ---- router: one block per token ----
        const int t = b - 1792;
        float part[E_];
#pragma unroll
        for (int e = 0; e < E_; ++e) part[e] = 0.f;

        const float* xr = x + (size_t)t * D_;
        for (int it = 0; it < D_ / 256; ++it) {
            int d = it * 256 + tid;
            float xv = xr[d];
            const float4* g4 = reinterpret_cast<const float4*>(gw + (size_t)d * E_);
#pragma unroll
            for (int q = 0; q < 4; ++q) {
                float4 gv = g4[q];
                part[q * 4 + 0] += xv * gv.x;
                part[q * 4 + 1] += xv * gv.y;
                part[q * 4 + 2] += xv * gv.z;
                part[q * 4 + 3] += xv * gv.w;
            }
        }
#pragma unroll
        for (int e = 0; e < E_; ++e) {
            float v = part[e];
#pragma unroll
            for (int off = 32; off > 0; off >>= 1) v += __shfl_down(v, off);
            part[e] = v;
        }
        const int wave = tid >> 6, lane = tid & 63;
        if (lane == 0) {
#pragma unroll
            for (int e = 0; e < E_; ++e) red[wave * E_ + e] = part[e];
        }
        __syncthreads();

        if (tid < E_) {
            float s = red[0 * E_ + tid] + red[1 * E_ + tid] + red[2 * E_ + tid] + red[3 * E_ + tid];
            s += bias[tid];
            sc[tid] = 1.f / (1.f + expf(-s));
        }
        __syncthreads();

        if (tid == 0) {
            float sum = 0.f;
#pragma unroll
            for (int e = 0; e < E_; ++e) sum += sc[e];
            float den = sum + EPS_;
            float ns[E_];
#pragma unroll
            for (int e = 0; e < E_; ++e) {
                ns[e] = sc[e] / den;
                nsc[(size_t)t * E_ + e] = ns[e];
            }
            bool used[E_];
#pragma unroll
            for (int e = 0; e < E_; ++e) used[e] = false;
            int sel[K_]; float selw[K_]; float wsum = 0.f;
            for (int k = 0; k < K_; ++k) {
                float best = -1.f; int bi = 0;
                for (int e = 0; e < E_; ++e)
                    if (!used[e] && ns[e] > best) { best = ns[e]; bi = e; }
                used[bi] = true; sel[k] = bi; selw[k] = best; wsum += best;
            }
            float wden = wsum + EPS_;
            for (int k = 0; k < K_; ++k) {
                int e = sel[k];
                int slot = atomicAdd(&cnt[e], 1);
                list_p[(size_t)e * T_ + slot] = t * K_ + k;
                list_w[(size_t)e * T_ + slot] = selw[k] / wden;
            }
        }
    }
}

// ================= GEMM1 (r5-proven): a = silu(x@w1)*(x@w3) =================
// BM=128, BN=64, BK=32; 4 waves; wave tile 64x32; single-buffered gll16 staging.
__global__ __launch_bounds__(256, 4) void gemm1_fast(
    const unsigned short* __restrict__ xhi, const unsigned short* __restrict__ xlo,
    const unsigned short* __restrict__ w1s, const unsigned short* __restrict__ w3s,
    const int* __restrict__ cnt, const int* __restrict__ list_p,
    unsigned short* __restrict__ a_hi, unsigned short* __restrict__ a_lo)
{
    const int bid = blockIdx.x;
    const int e   = bid >> 8;
    const int rem = bid & 255;
    const int mt  = rem >> 4;
    const int nt  = rem & 15;
    const int ne  = cnt[e];
    if (mt * 128 >= ne) return;
    const int tid = threadIdx.x;

    __shared__ int ps[128];
    __shared__ int ts[128];
    __shared__ alignas(16) unsigned short Ah[4096], Al[4096];       // 128x32
    __shared__ alignas(16) unsigned short B1h[2048], B1l[2048];     // 32x64
    __shared__ alignas(16) unsigned short B3h[2048], B3l[2048];

    if (tid < 128) {
        int slot = mt * 128 + tid;
        if (slot < ne) { int p = list_p[(size_t)e * T_ + slot]; ps[tid] = p; ts[tid] = p >> 2; }
        else           { ps[tid] = -1; ts[tid] = 0; }
    }
    __syncthreads();

    const int mf0 = tid >> 6, kc0 = (tid >> 4) & 3, r16 = tid & 15;
    const unsigned short* axh0 = xhi + (size_t)ts[mf0 * 16 + r16] * D_ + kc0 * 8;
    const unsigned short* axl0 = xlo + (size_t)ts[mf0 * 16 + r16] * D_ + kc0 * 8;
    const unsigned short* axh1 = xhi + (size_t)ts[(mf0 + 4) * 16 + r16] * D_ + kc0 * 8;
    const unsigned short* axl1 = xlo + (size_t)ts[(mf0 + 4) * 16 + r16] * D_ + kc0 * 8;

    const unsigned short* b1base = w1s + ((size_t)(e * 16 + nt) * 32) * 4096;
    const unsigned short* b3base = w3s + ((size_t)(e * 16 + nt) * 32) * 4096;

    const int w = tid >> 6, l = tid & 63;
    const int wr = w >> 1, wc = w & 1;
    const int lo8 = l * 8;

    floatx4 acch[4][2], accg[4][2];
#pragma unroll
    for (int i = 0; i < 4; ++i)
#pragma unroll
        for (int j = 0; j < 2; ++j) { acch[i][j] = (floatx4)0.f; accg[i][j] = (floatx4)0.f; }

    for (int k0 = 0; k0 < D_; k0 += 32) {
        const unsigned short* b1 = b1base + (size_t)(k0 >> 5) * 4096;
        const unsigned short* b3 = b3base + (size_t)(k0 >> 5) * 4096;
        gll16(axh0 + k0, Ah + tid * 8);
        gll16(axh1 + k0, Ah + (tid + 256) * 8);
        gll16(axl0 + k0, Al + tid * 8);
        gll16(axl1 + k0, Al + (tid + 256) * 8);
        gll16(b1 + tid * 8,        B1h + tid * 8);
        gll16(b1 + 2048 + tid * 8, B1l + tid * 8);
        gll16(b3 + tid * 8,        B3h + tid * 8);
        gll16(b3 + 2048 + tid * 8, B3l + tid * 8);
        __syncthreads();

        short8 ah[4], al[4];
#pragma unroll
        for (int mi = 0; mi < 4; ++mi) {
            int base = (wr * 4 + mi) * 512 + lo8;
            ah[mi] = *reinterpret_cast<const short8*>(Ah + base);
            al[mi] = *reinterpret_cast<const short8*>(Al + base);
        }
#pragma unroll
        for (int nj = 0; nj < 2; ++nj) {
            int bb = (wc * 2 + nj) * 512 + lo8;
            short8 b1hv = *reinterpret_cast<const short8*>(B1h + bb);
            short8 b1lv = *reinterpret_cast<const short8*>(B1l + bb);
            short8 b3hv = *reinterpret_cast<const short8*>(B3h + bb);
            short8 b3lv = *reinterpret_cast<const short8*>(B3l + bb);
#pragma unroll
            for (int mi = 0; mi < 4; ++mi) {
                acch[mi][nj] = MFMA16(ah[mi], b1hv, acch[mi][nj]);
                acch[mi][nj] = MFMA16(al[mi], b1hv, acch[mi][nj]);
                acch[mi][nj] = MFMA16(ah[mi], b1lv, acch[mi][nj]);
                accg[mi][nj] = MFMA16(ah[mi], b3hv, accg[mi][nj]);
                accg[mi][nj] = MFMA16(al[mi], b3hv, accg[mi][nj]);
                accg[mi][nj] = MFMA16(ah[mi], b3lv, accg[mi][nj]);
            }
        }
        __syncthreads();
    }

    const int g4 = (l >> 4) * 4;
#pragma unroll
    for (int mi = 0; mi < 4; ++mi) {
#pragma unroll
        for (int r = 0; r < 4; ++r) {
            int m = wr * 64 + mi * 16 + g4 + r;
            int p = ps[m];
            if (p < 0) continue;
            size_t ro = (size_t)p * H_ + nt * 64 + wc * 32 + (l & 15);
#pragma unroll
            for (int nj = 0; nj < 2; ++nj) {
                float h = acch[mi][nj][r];
                float g = accg[mi][nj][r];
                float a = silu_f(h) * g;
                unsigned b = __float_as_uint(a);
                float rr = a - __uint_as_float(b & 0xFFFF0000u);
                a_hi[ro + nj * 16] = (unsigned short)(b >> 16);
                a_lo[ro + nj * 16] = (unsigned short)(__float_as_uint(rr) >> 16);
            }
        }
    }
}

// ================= GEMM2 (r7-proven) + folded lb block =================
// BM=128, BN=128, single-buffered, XCD swizzle; block 2048 computes lb_loss.
__global__ __launch_bounds__(256, 3) void gemm2_fast(
    const unsigned short* __restrict__ a_hi, const unsigned short* __restrict__ a_lo,
    const unsigned short* __restrict__ w2s, const int* __restrict__ cnt,
    const int* __restrict__ list_p, const float* __restrict__ list_w,
    const float* __restrict__ nsc, float* __restrict__ out)
{
    const int tid = threadIdx.x;

    if (blockIdx.x == 2048) {
        // ---- lb_loss ----
        float part[E_];
#pragma unroll
        for (int e = 0; e < E_; ++e) part[e] = 0.f;
        for (int t = tid; t < T_; t += 256) {
            const float4* r4 = reinterpret_cast<const float4*>(nsc + (size_t)t * E_);
#pragma unroll
            for (int q = 0; q < 4; ++q) {
                float4 v = r4[q];
                part[q * 4 + 0] += v.x; part[q * 4 + 1] += v.y;
                part[q * 4 + 2] += v.z; part[q * 4 + 3] += v.w;
            }
        }
#pragma unroll
        for (int e = 0; e < E_; ++e) {
            float v = part[e];
#pragma unroll
            for (int off = 32; off > 0; off >>= 1) v += __shfl_down(v, off);
            part[e] = v;
        }
        __shared__ float red[4 * E_];
        const int wave = tid >> 6, lane = tid & 63;
        if (lane == 0) {
#pragma unroll
            for (int e = 0; e < E_; ++e) red[wave * E_ + e] = part[e];
        }
        __syncthreads();
        if (tid == 0) {
            float lb = 0.f;
            for (int e = 0; e < E_; ++e) {
                float s = red[0 * E_ + e] + red[1 * E_ + e] + red[2 * E_ + e] + red[3 * E_ + e];
                lb += ((float)cnt[e] / (float)T_) * (s / (float)T_);
            }
            out[(size_t)T_ * D_] = (float)E_ * lb;
        }
        return;
    }

    const int bid0 = blockIdx.x;
    const int bid  = (bid0 & 7) * 256 + (bid0 >> 3);   // bijective XCD swizzle over 2048
    const int e   = bid >> 7;
    const int rem = bid & 127;
    const int mt  = rem >> 3;
    const int ntb = rem & 7;
    const int ne  = cnt[e];
    if (mt * 128 >= ne) return;

    __shared__ int   ps[128];
    __shared__ float wts[128];
    __shared__ alignas(16) unsigned short Ahs[4096], Als[4096];
    __shared__ alignas(16) unsigned short Bh[4096], Bl[4096];

    if (tid < 128) {
        int slot = mt * 128 + tid;
        if (slot < ne) {
            int p = list_p[(size_t)e * T_ + slot];
            ps[tid] = p; wts[tid] = list_w[(size_t)e * T_ + slot];
        } else { ps[tid] = -1; wts[tid] = 0.f; }
    }
    __syncthreads();

    const int mf0 = tid >> 6, kc0 = (tid >> 4) & 3, r16 = tid & 15;
    int p0 = ps[mf0 * 16 + r16];      if (p0 < 0) p0 = 0;
    int p1 = ps[mf0 * 16 + 64 + r16]; if (p1 < 0) p1 = 0;
    const unsigned short* aah0 = a_hi + (size_t)p0 * H_ + kc0 * 8;
    const unsigned short* aal0 = a_lo + (size_t)p0 * H_ + kc0 * 8;
    const unsigned short* aah1 = a_hi + (size_t)p1 * H_ + kc0 * 8;
    const unsigned short* aal1 = a_lo + (size_t)p1 * H_ + kc0 * 8;

    const unsigned short* b2a = w2s + ((size_t)(e * 16 + ntb * 2)     * 32) * 4096 + tid * 8;
    const unsigned short* b2b = w2s + ((size_t)(e * 16 + ntb * 2 + 1) * 32) * 4096 + tid * 8;

    const int w = tid >> 6, l = tid & 63;
    const int wr = w >> 1, wc = w & 1;
    const int lo8 = l * 8;

    floatx4 acc[4][4];
#pragma unroll
    for (int i = 0; i < 4; ++i)
#pragma unroll
        for (int j = 0; j < 4; ++j) acc[i][j] = (floatx4)0.f;

    for (int k0 = 0; k0 < H_; k0 += 32) {
        const int ksoff = (k0 >> 5) * 4096;
        gll16(aah0 + k0, Ahs + tid * 8);
        gll16(aah1 + k0, Ahs + (tid + 256) * 8);
        gll16(aal0 + k0, Als + tid * 8);
        gll16(aal1 + k0, Als + (tid + 256) * 8);
        gll16(b2a + ksoff,        Bh + tid * 8);
        gll16(b2b + ksoff,        Bh + (tid + 256) * 8);
        gll16(b2a + ksoff + 2048, Bl + tid * 8);
        gll16(b2b + ksoff + 2048, Bl + (tid + 256) * 8);
        __syncthreads();

        short8 ah[4], al[4];
#pragma unroll
        for (int mi = 0; mi < 4; ++mi) {
            int base = (wr * 4 + mi) * 512 + lo8;
            ah[mi] = *reinterpret_cast<const short8*>(Ahs + base);
            al[mi] = *reinterpret_cast<const short8*>(Als + base);
        }
#pragma unroll
        for (int nj = 0; nj < 4; ++nj) {
            int bb = (wc * 4 + nj) * 512 + lo8;
            short8 bhv = *reinterpret_cast<const short8*>(Bh + bb);
            short8 blv = *reinterpret_cast<const short8*>(Bl + bb);
#pragma unroll
            for (int mi = 0; mi < 4; ++mi) {
                acc[mi][nj] = MFMA16(ah[mi], bhv, acc[mi][nj]);
                acc[mi][nj] = MFMA16(al[mi], bhv, acc[mi][nj]);
                acc[mi][nj] = MFMA16(ah[mi], blv, acc[mi][nj]);
            }
        }
        __syncthreads();
    }

    const int g4 = (l >> 4) * 4;
#pragma unroll
    for (int mi = 0; mi < 4; ++mi) {
#pragma unroll
        for (int r = 0; r < 4; ++r) {
            int m = wr * 64 + mi * 16 + g4 + r;
            int p = ps[m];
            if (p < 0) continue;
            int t = p >> 2;
            float wt = wts[m];
            float* dst = out + (size_t)t * D_ + ntb * 128 + wc * 64 + (l & 15);
#pragma unroll
            for (int nj = 0; nj < 4; ++nj)
                atomicAdd(dst + nj * 16, wt * acc[mi][nj][r]);
        }
    }
}

// ================= launch =================
extern "C" void kernel_launch(void* const* d_in, const int* in_sizes, int n_in,
                              void* d_out, int out_size, void* d_ws, size_t ws_size,
                              hipStream_t stream)
{
    const float* x    = (const float*)d_in[0];
    const float* gw   = (const float*)d_in[1];
    const float* bias = (const float*)d_in[2];
    const float* w1   = (const float*)d_in[3];
    const float* w3   = (const float*)d_in[4];
    const float* w2   = (const float*)d_in[5];
    float* out = (float*)d_out;
    char*  ws  = (char*)d_ws;

    int*   cnt    = (int*)  (ws + FWS_CNT);
    int*   list_p = (int*)  (ws + FWS_LISTP);
    float* list_w = (float*)(ws + FWS_LISTW);
    float* nsc    = (float*)(ws + FWS_NSC);
    unsigned short* xhi  = (unsigned short*)(ws + FWS_XHI);
    unsigned short* xlo  = (unsigned short*)(ws + FWS_XLO);
    unsigned short* a_hi = (unsigned short*)(ws + FWS_AHI);
    unsigned short* a_lo = (unsigned short*)(ws + FWS_ALO);
    unsigned short* w1s  = (unsigned short*)(ws + FWS_W1S);
    unsigned short* w3s  = (unsigned short*)(ws + FWS_W3S);
    unsigned short* w2s  = (unsigned short*)(ws + FWS_W2S);

    hipMemsetAsync(d_out, 0, (size_t)out_size * sizeof(float), stream);
    hipMemsetAsync(ws, 0, 256, stream);   // cnt

    pre_kernel<<<3840, 256, 0, stream>>>(w1, w3, w2, w1s, w3s, w2s,
                                         x, xhi, xlo, gw, bias,
                                         cnt, nsc, list_p, list_w);
    gemm1_fast<<<4096, 256, 0, stream>>>(xhi, xlo, w1s, w3s, cnt, list_p, a_hi, a_lo);
    gemm2_fast<<<2049, 256, 0, stream>>>(a_hi, a_lo, w2s, cnt, list_p, list_w, nsc, out);
}